// Round 7
// baseline (261.739 us; speedup 1.0000x reference)
//
#include <hip/hip_runtime.h>

#define BB 4
#define NN 2048
#define FF 128
#define NP 2176  // padded WhT row stride (shorts)
#define ALPHA 0.2f
#define SHIFT_C 16.0f  // exp(x-16): x=LR(f1+f2) bounded ~|10|; masked -> p=0 via bit-multiply

typedef short bf16x8 __attribute__((ext_vector_type(8)));
typedef float f32x4 __attribute__((ext_vector_type(4)));
typedef unsigned u32;

__device__ inline short f2bf(float f) {  // RNE float -> bf16 bits
    union { float f; unsigned u; } v; v.f = f;
    unsigned r = (v.u + 0x7FFFu + ((v.u >> 16) & 1u)) >> 16;
    return (short)r;
}
__device__ inline float bf2f(short s) {
    union { float f; unsigned u; } v;
    v.u = ((unsigned)(unsigned short)s) << 16;
    return v.f;
}

// ---------------------------------------------------------------------------
// k_wh: unchanged (passed).
// ---------------------------------------------------------------------------
__global__ __launch_bounds__(256) void k_wh(const float* __restrict__ h,
                                            const float* __restrict__ W,
                                            const float* __restrict__ a,
                                            const int* __restrict__ adj,
                                            short* __restrict__ WhHiT,
                                            short* __restrict__ WhLoT,
                                            float* __restrict__ f1,
                                            float* __restrict__ f2,
                                            u32* __restrict__ adjp) {
    __shared__ float Wa[2 * FF];
    __shared__ float hs[16 * 128];  // 8 KB
    int tid = threadIdx.x;
    int r0 = blockIdx.x * 16;

    {
        int fin = tid & 127;
        const float* av = (tid < 128) ? a : (a + FF);
        const float* wr = W + (size_t)fin * FF;
        float s = 0.f;
        for (int o = 0; o < FF; o += 4) {
            float4 wv = *(const float4*)(wr + o);
            float4 avv = *(const float4*)(av + o);
            s += wv.x * avv.x + wv.y * avv.y + wv.z * avv.z + wv.w * avv.w;
        }
        Wa[(tid < 128 ? 0 : FF) + fin] = s;
    }
    {
        const float4* src = (const float4*)(h + (size_t)r0 * FF);
        float4* dst = (float4*)hs;
        dst[tid] = src[tid];
        dst[256 + tid] = src[256 + tid];
    }
    // de-serialized adj pack: 512 blocks * 256 thr = 131072 = 2048 rows * 64 words
    {
        int g = blockIdx.x * 256 + tid;
        int row = g >> 6, wd = g & 63;
        const int4* ar = (const int4*)(adj + (size_t)row * NN + wd * 32);
        u32 word = 0;
#pragma unroll
        for (int q = 0; q < 8; ++q) {
            int4 v = ar[q];
            word |= (u32)(v.x > 0) << (q * 4);
            word |= (u32)(v.y > 0) << (q * 4 + 1);
            word |= (u32)(v.z > 0) << (q * 4 + 2);
            word |= (u32)(v.w > 0) << (q * 4 + 3);
        }
        adjp[row * 64 + wd] = word;
    }
    __syncthreads();

    {
        int w = tid >> 6, lane = tid & 63;
        float wa1_0 = Wa[lane], wa1_1 = Wa[lane + 64];
        float wa2_0 = Wa[FF + lane], wa2_1 = Wa[FF + lane + 64];
        for (int rr = 0; rr < 4; ++rr) {
            int rloc = w * 4 + rr;
            int row = r0 + rloc;
            float x0 = hs[rloc * FF + lane], x1 = hs[rloc * FF + lane + 64];
            float s1 = x0 * wa1_0 + x1 * wa1_1;
            float s2 = x0 * wa2_0 + x1 * wa2_1;
#pragma unroll
            for (int m = 32; m >= 1; m >>= 1) {
                s1 += __shfl_xor(s1, m, 64);
                s2 += __shfl_xor(s2, m, 64);
            }
            if (lane == 0) { f1[row] = s1; f2[row] = s2; }
        }
    }

    int f4 = (tid & 31) * 4;
    int rg = tid >> 5;  // 0..7
    float acc[2][4];
#pragma unroll
    for (int rr = 0; rr < 2; ++rr)
#pragma unroll
        for (int cc = 0; cc < 4; ++cc) acc[rr][cc] = 0.f;

    for (int k0 = 0; k0 < FF; k0 += 4) {
        float4 wv[4];
#pragma unroll
        for (int kk = 0; kk < 4; ++kk)
            wv[kk] = *(const float4*)(W + (size_t)(k0 + kk) * FF + f4);
        float4 hv[2];
#pragma unroll
        for (int rr = 0; rr < 2; ++rr)
            hv[rr] = *(const float4*)(hs + (rg * 2 + rr) * FF + k0);
#pragma unroll
        for (int rr = 0; rr < 2; ++rr) {
            float hk[4] = {hv[rr].x, hv[rr].y, hv[rr].z, hv[rr].w};
#pragma unroll
            for (int kk = 0; kk < 4; ++kk) {
                acc[rr][0] += hk[kk] * wv[kk].x;
                acc[rr][1] += hk[kk] * wv[kk].y;
                acc[rr][2] += hk[kk] * wv[kk].z;
                acc[rr][3] += hk[kk] * wv[kk].w;
            }
        }
    }
    int rloc = r0 + rg * 2;
    int b = rloc >> 11;
    int j = rloc & (NN - 1);  // even
#pragma unroll
    for (int cc = 0; cc < 4; ++cc) {
        float v0 = acc[0][cc], v1 = acc[1][cc];
        short h0 = f2bf(v0), h1 = f2bf(v1);
        short l0 = f2bf(v0 - bf2f(h0)), l1 = f2bf(v1 - bf2f(h1));
        size_t off = (size_t)(b * FF + f4 + cc) * NP + j;
        *(short2*)(WhHiT + off) = make_short2(h0, h1);
        *(short2*)(WhLoT + off) = make_short2(l0, l1);
    }
}

// ---------------------------------------------------------------------------
// k_attn v11 "double TLP": v10's counters showed VGPR=64 (allocator found a
// no-spill 64-reg schedule by SERIALIZING B consumption: ~8 sequential L2
// round trips/step) with only 4 waves/SIMD resident (occupancy 38%) ->
// latency-bound. 64 VGPR natively supports 8 waves/SIMD; total waves was
// the limit. v11: 16 waves/block (1024 thr) x 4 j-steps each (same total
// work, same per-step body) -> 8192 waves, 32/CU, 8/SIMD = the 64-VGPR
// occupancy ceiling (64 x 2048 thr = 131072 = full RF). Merge LDS shrunk
// to fit 2 blocks/CU: tree merge through 8 buffers (waves 0-7 write,
// waves 8-15 RMW-add after one barrier) -> LDS 67.7KB. waves_per_eu(8,8)
// pins the allocator at <=64 VGPR (v10 proved this body fits without
// spill). Main-loop body and final merge/store identical to v8-v10.
// ---------------------------------------------------------------------------
#define EV(f2v, f1v, wv, bi) ({ float _t = (f1v) + (f2v); float _x = fmaxf(_t, ALPHA * _t); \
    __expf(_x - SHIFT_C) * (float)(((wv) >> (bi)) & 1u); })

__global__ __launch_bounds__(1024) __attribute__((amdgpu_waves_per_eu(8, 8)))
void k_attn(const short* __restrict__ WhHiT,
            const short* __restrict__ WhLoT,
            const u32* __restrict__ adjp,
            const float* __restrict__ f1,
            const float* __restrict__ f2,
            float* __restrict__ out) {
    __shared__ __align__(16) char lds[67712];  // 8 x 8KB merge bufs + row_ps 2KB + row_inv 128B
    float* row_ps = (float*)(lds + 65536);     // [16][32]
    float* row_inv = (float*)(lds + 67584);    // [32]

    int tid = threadIdx.x;
    int w = tid >> 6, lane = tid & 63;         // w 0..15
    int blk = blockIdx.x;
    int b = blk >> 7;
    int tile = (blk >> 1) & 63;
    int half = blk & 1;
    int i0 = tile * 32;

    int r_c = lane & 15, kg = lane >> 4;

    const float* f2b = f2 + b * NN;
    float f10 = f1[b * NN + i0 + r_c];        // mi=0 row
    float f11 = f1[b * NN + i0 + 16 + r_c];   // mi=1 row
    const u32* ap0 = adjp + (size_t)(i0 + r_c) * 64;
    const u32* ap1 = adjp + (size_t)(i0 + 16 + r_c) * 64;

    // B-fragment row pointers (hi); lo at constant element delta
    const ptrdiff_t dLo = (ptrdiff_t)BB * FF * NP;
    int s0 = w * 4;  // this wave's first step (contiguous 4 steps; 16 waves cover 64)
    const short* pB0 = WhHiT + (size_t)(b * FF + half * 64 + 0 * 16 + r_c) * NP + s0 * 32 + kg * 8;
    const short* pB1 = WhHiT + (size_t)(b * FF + half * 64 + 1 * 16 + r_c) * NP + s0 * 32 + kg * 8;
    const short* pB2 = WhHiT + (size_t)(b * FF + half * 64 + 2 * 16 + r_c) * NP + s0 * 32 + kg * 8;
    const short* pB3 = WhHiT + (size_t)(b * FF + half * 64 + 3 * 16 + r_c) * NP + s0 * 32 + kg * 8;

    f32x4 acc0_0 = {0,0,0,0}, acc0_1 = {0,0,0,0};
    f32x4 acc1_0 = {0,0,0,0}, acc1_1 = {0,0,0,0};
    f32x4 acc2_0 = {0,0,0,0}, acc2_1 = {0,0,0,0};
    f32x4 acc3_0 = {0,0,0,0}, acc3_1 = {0,0,0,0};
    float sp0 = 0.f, sp1 = 0.f;

#pragma unroll 1
    for (int s8 = 0; s8 < 4; ++s8) {
        int s = s0 + s8;
        // scalars for EV
        float4 q0 = *(const float4*)(f2b + s * 32 + kg * 8);
        float4 q1 = *(const float4*)(f2b + s * 32 + kg * 8 + 4);
        u32 w0 = ap0[s], w1 = ap1[s];
        // B loads for this step (8 x 16B; in flight during EV compute)
        bf16x8 bh0 = *(const bf16x8*)(pB0); bf16x8 bl0 = *(const bf16x8*)(pB0 + dLo);
        bf16x8 bh1 = *(const bf16x8*)(pB1); bf16x8 bl1 = *(const bf16x8*)(pB1 + dLo);
        bf16x8 bh2 = *(const bf16x8*)(pB2); bf16x8 bl2 = *(const bf16x8*)(pB2 + dLo);
        bf16x8 bh3 = *(const bf16x8*)(pB3); bf16x8 bl3 = *(const bf16x8*)(pB3 + dLo);

        // in-register A fragments: lane holds rows r_c (mi=0), 16+r_c (mi=1),
        // k-elements j = s*32 + kg*8 + e  (bit kg*8+e of adjp word s)
        union { u32 u[4]; bf16x8 v; } A0, A1;
        int bb = kg * 8;
        {
            float pa, pb;
            pa = EV(q0.x, f10, w0, bb + 0); pb = EV(q0.y, f10, w0, bb + 1);
            sp0 += pa + pb;
            asm("v_cvt_pk_bf16_f32 %0, %1, %2" : "=v"(A0.u[0]) : "v"(pa), "v"(pb));
            pa = EV(q0.z, f10, w0, bb + 2); pb = EV(q0.w, f10, w0, bb + 3);
            sp0 += pa + pb;
            asm("v_cvt_pk_bf16_f32 %0, %1, %2" : "=v"(A0.u[1]) : "v"(pa), "v"(pb));
            pa = EV(q1.x, f10, w0, bb + 4); pb = EV(q1.y, f10, w0, bb + 5);
            sp0 += pa + pb;
            asm("v_cvt_pk_bf16_f32 %0, %1, %2" : "=v"(A0.u[2]) : "v"(pa), "v"(pb));
            pa = EV(q1.z, f10, w0, bb + 6); pb = EV(q1.w, f10, w0, bb + 7);
            sp0 += pa + pb;
            asm("v_cvt_pk_bf16_f32 %0, %1, %2" : "=v"(A0.u[3]) : "v"(pa), "v"(pb));

            pa = EV(q0.x, f11, w1, bb + 0); pb = EV(q0.y, f11, w1, bb + 1);
            sp1 += pa + pb;
            asm("v_cvt_pk_bf16_f32 %0, %1, %2" : "=v"(A1.u[0]) : "v"(pa), "v"(pb));
            pa = EV(q0.z, f11, w1, bb + 2); pb = EV(q0.w, f11, w1, bb + 3);
            sp1 += pa + pb;
            asm("v_cvt_pk_bf16_f32 %0, %1, %2" : "=v"(A1.u[1]) : "v"(pa), "v"(pb));
            pa = EV(q1.x, f11, w1, bb + 4); pb = EV(q1.y, f11, w1, bb + 5);
            sp1 += pa + pb;
            asm("v_cvt_pk_bf16_f32 %0, %1, %2" : "=v"(A1.u[2]) : "v"(pa), "v"(pb));
            pa = EV(q1.z, f11, w1, bb + 6); pb = EV(q1.w, f11, w1, bb + 7);
            sp1 += pa + pb;
            asm("v_cvt_pk_bf16_f32 %0, %1, %2" : "=v"(A1.u[3]) : "v"(pa), "v"(pb));
        }

        // 8 MFMA-pairs: out = A x (Bhi + Blo), both halves into the same acc
        acc0_0 = __builtin_amdgcn_mfma_f32_16x16x32_bf16(A0.v, bh0, acc0_0, 0, 0, 0);
        acc0_0 = __builtin_amdgcn_mfma_f32_16x16x32_bf16(A0.v, bl0, acc0_0, 0, 0, 0);
        acc0_1 = __builtin_amdgcn_mfma_f32_16x16x32_bf16(A1.v, bh0, acc0_1, 0, 0, 0);
        acc0_1 = __builtin_amdgcn_mfma_f32_16x16x32_bf16(A1.v, bl0, acc0_1, 0, 0, 0);
        acc1_0 = __builtin_amdgcn_mfma_f32_16x16x32_bf16(A0.v, bh1, acc1_0, 0, 0, 0);
        acc1_0 = __builtin_amdgcn_mfma_f32_16x16x32_bf16(A0.v, bl1, acc1_0, 0, 0, 0);
        acc1_1 = __builtin_amdgcn_mfma_f32_16x16x32_bf16(A1.v, bh1, acc1_1, 0, 0, 0);
        acc1_1 = __builtin_amdgcn_mfma_f32_16x16x32_bf16(A1.v, bl1, acc1_1, 0, 0, 0);
        acc2_0 = __builtin_amdgcn_mfma_f32_16x16x32_bf16(A0.v, bh2, acc2_0, 0, 0, 0);
        acc2_0 = __builtin_amdgcn_mfma_f32_16x16x32_bf16(A0.v, bl2, acc2_0, 0, 0, 0);
        acc2_1 = __builtin_amdgcn_mfma_f32_16x16x32_bf16(A1.v, bh2, acc2_1, 0, 0, 0);
        acc2_1 = __builtin_amdgcn_mfma_f32_16x16x32_bf16(A1.v, bl2, acc2_1, 0, 0, 0);
        acc3_0 = __builtin_amdgcn_mfma_f32_16x16x32_bf16(A0.v, bh3, acc3_0, 0, 0, 0);
        acc3_0 = __builtin_amdgcn_mfma_f32_16x16x32_bf16(A0.v, bl3, acc3_0, 0, 0, 0);
        acc3_1 = __builtin_amdgcn_mfma_f32_16x16x32_bf16(A1.v, bh3, acc3_1, 0, 0, 0);
        acc3_1 = __builtin_amdgcn_mfma_f32_16x16x32_bf16(A1.v, bl3, acc3_1, 0, 0, 0);

        pB0 += 32; pB1 += 32; pB2 += 32; pB3 += 32;
    }

    // ---- epilogue: tree merge 16 partial images through 8 buffers ----
    sp0 += __shfl_xor(sp0, 16, 64); sp0 += __shfl_xor(sp0, 32, 64);
    sp1 += __shfl_xor(sp1, 16, 64); sp1 += __shfl_xor(sp1, 32, 64);
    if (lane < 16) {
        row_ps[w * 32 + lane] = sp0;
        row_ps[w * 32 + 16 + lane] = sp1;
    }
    // round A: waves 0-7 write their partial image (col-major, XOR-swizzled)
    if (w < 8) {
        char* img = lds + w * 8192;
#define STACC(NI, MI, A) { int ch = (((NI)*16 + r_c) * 8 + (MI)*4 + kg) ^ (r_c & 7); \
                           *(f32x4*)(img + ch * 16) = (A); }
        STACC(0, 0, acc0_0) STACC(0, 1, acc0_1)
        STACC(1, 0, acc1_0) STACC(1, 1, acc1_1)
        STACC(2, 0, acc2_0) STACC(2, 1, acc2_1)
        STACC(3, 0, acc3_0) STACC(3, 1, acc3_1)
#undef STACC
    }
    __syncthreads();
    // round B: waves 8-15 RMW-add into buffer (w-8); wave 0's first lanes do row_inv
    if (w >= 8) {
        char* img = lds + (w - 8) * 8192;
#define MRGACC(NI, MI, A) { int ch = (((NI)*16 + r_c) * 8 + (MI)*4 + kg) ^ (r_c & 7); \
                            f32x4* p = (f32x4*)(img + ch * 16); *p = *p + (A); }
        MRGACC(0, 0, acc0_0) MRGACC(0, 1, acc0_1)
        MRGACC(1, 0, acc1_0) MRGACC(1, 1, acc1_1)
        MRGACC(2, 0, acc2_0) MRGACC(2, 1, acc2_1)
        MRGACC(3, 0, acc3_0) MRGACC(3, 1, acc3_1)
#undef MRGACC
    } else if (tid < 32) {
        float t = 0.f;
#pragma unroll
        for (int ww = 0; ww < 16; ++ww) t += row_ps[ww * 32 + tid];
        row_inv[tid] = 1.0f / t;
    }
    __syncthreads();

    // final: merge 8 buffers + normalize + store (waves 0-7; mapping as v8)
    if (w < 8) {
        int colg = w * 8 + (lane >> 3);
        int rq = lane & 7;
        int ch = (colg * 8 + rq) ^ (colg & 7);
        f32x4 v = {0, 0, 0, 0};
#pragma unroll
        for (int im = 0; im < 8; ++im)
            v += *(const f32x4*)(lds + im * 8192 + ch * 16);
        f32x4 rinv = *(const f32x4*)((char*)row_inv + rq * 16);
        float* ob = out + ((size_t)b * NN + i0 + rq * 4) * FF + half * 64 + colg;
#pragma unroll
        for (int q = 0; q < 4; ++q)
            ob[(size_t)q * FF] = v[q] * rinv[q];
    }
}

// ---------------------------------------------------------------------------
extern "C" void kernel_launch(void* const* d_in, const int* in_sizes, int n_in,
                              void* d_out, int out_size, void* d_ws, size_t ws_size,
                              hipStream_t stream) {
    const float* h   = (const float*)d_in[0];
    const int*   adj = (const int*)d_in[1];
    const float* W   = (const float*)d_in[2];
    const float* a   = (const float*)d_in[3];
    float* out = (float*)d_out;

    short* WhHiT = (short*)d_ws;                          // 2.13 MB
    short* WhLoT = WhHiT + (size_t)BB * FF * NP;          // 2.13 MB
    float* f1 = (float*)(WhLoT + (size_t)BB * FF * NP);   // 32 KB
    float* f2 = f1 + (size_t)BB * NN;                     // 32 KB
    u32* adjp = (u32*)(f2 + (size_t)BB * NN);             // 512 KB (total ~4.83 MB, proven)

    k_wh<<<(BB * NN) / 16, 256, 0, stream>>>(h, W, a, adj, WhHiT, WhLoT, f1, f2, adjp);
    k_attn<<<512, 1024, 0, stream>>>(WhHiT, WhLoT, adjp, f1, f2, out);
}

// Round 9
// 241.544 us; speedup vs baseline: 1.0836x; 1.0836x over previous
//
#include <hip/hip_runtime.h>

#define BB 4
#define NN 2048
#define FF 128
#define NP 2176  // padded WhT row stride (shorts)
#define ALPHA 0.2f
#define SHIFT_C 16.0f  // exp(x-16): x=LR(f1+f2) bounded ~|10|; masked -> p=0 via bit-multiply

typedef short bf16x8 __attribute__((ext_vector_type(8)));
typedef float f32x4 __attribute__((ext_vector_type(4)));
typedef unsigned u32;

__device__ inline short f2bf(float f) {  // RNE float -> bf16 bits
    union { float f; unsigned u; } v; v.f = f;
    unsigned r = (v.u + 0x7FFFu + ((v.u >> 16) & 1u)) >> 16;
    return (short)r;
}
__device__ inline float bf2f(short s) {
    union { float f; unsigned u; } v;
    v.u = ((unsigned)(unsigned short)s) << 16;
    return v.f;
}

// ---------------------------------------------------------------------------
// k_wh: unchanged (passed).
// ---------------------------------------------------------------------------
__global__ __launch_bounds__(256) void k_wh(const float* __restrict__ h,
                                            const float* __restrict__ W,
                                            const float* __restrict__ a,
                                            const int* __restrict__ adj,
                                            short* __restrict__ WhHiT,
                                            short* __restrict__ WhLoT,
                                            float* __restrict__ f1,
                                            float* __restrict__ f2,
                                            u32* __restrict__ adjp) {
    __shared__ float Wa[2 * FF];
    __shared__ float hs[16 * 128];  // 8 KB
    int tid = threadIdx.x;
    int r0 = blockIdx.x * 16;

    {
        int fin = tid & 127;
        const float* av = (tid < 128) ? a : (a + FF);
        const float* wr = W + (size_t)fin * FF;
        float s = 0.f;
        for (int o = 0; o < FF; o += 4) {
            float4 wv = *(const float4*)(wr + o);
            float4 avv = *(const float4*)(av + o);
            s += wv.x * avv.x + wv.y * avv.y + wv.z * avv.z + wv.w * avv.w;
        }
        Wa[(tid < 128 ? 0 : FF) + fin] = s;
    }
    {
        const float4* src = (const float4*)(h + (size_t)r0 * FF);
        float4* dst = (float4*)hs;
        dst[tid] = src[tid];
        dst[256 + tid] = src[256 + tid];
    }
    // de-serialized adj pack: 512 blocks * 256 thr = 131072 = 2048 rows * 64 words
    {
        int g = blockIdx.x * 256 + tid;
        int row = g >> 6, wd = g & 63;
        const int4* ar = (const int4*)(adj + (size_t)row * NN + wd * 32);
        u32 word = 0;
#pragma unroll
        for (int q = 0; q < 8; ++q) {
            int4 v = ar[q];
            word |= (u32)(v.x > 0) << (q * 4);
            word |= (u32)(v.y > 0) << (q * 4 + 1);
            word |= (u32)(v.z > 0) << (q * 4 + 2);
            word |= (u32)(v.w > 0) << (q * 4 + 3);
        }
        adjp[row * 64 + wd] = word;
    }
    __syncthreads();

    {
        int w = tid >> 6, lane = tid & 63;
        float wa1_0 = Wa[lane], wa1_1 = Wa[lane + 64];
        float wa2_0 = Wa[FF + lane], wa2_1 = Wa[FF + lane + 64];
        for (int rr = 0; rr < 4; ++rr) {
            int rloc = w * 4 + rr;
            int row = r0 + rloc;
            float x0 = hs[rloc * FF + lane], x1 = hs[rloc * FF + lane + 64];
            float s1 = x0 * wa1_0 + x1 * wa1_1;
            float s2 = x0 * wa2_0 + x1 * wa2_1;
#pragma unroll
            for (int m = 32; m >= 1; m >>= 1) {
                s1 += __shfl_xor(s1, m, 64);
                s2 += __shfl_xor(s2, m, 64);
            }
            if (lane == 0) { f1[row] = s1; f2[row] = s2; }
        }
    }

    int f4 = (tid & 31) * 4;
    int rg = tid >> 5;  // 0..7
    float acc[2][4];
#pragma unroll
    for (int rr = 0; rr < 2; ++rr)
#pragma unroll
        for (int cc = 0; cc < 4; ++cc) acc[rr][cc] = 0.f;

    for (int k0 = 0; k0 < FF; k0 += 4) {
        float4 wv[4];
#pragma unroll
        for (int kk = 0; kk < 4; ++kk)
            wv[kk] = *(const float4*)(W + (size_t)(k0 + kk) * FF + f4);
        float4 hv[2];
#pragma unroll
        for (int rr = 0; rr < 2; ++rr)
            hv[rr] = *(const float4*)(hs + (rg * 2 + rr) * FF + k0);
#pragma unroll
        for (int rr = 0; rr < 2; ++rr) {
            float hk[4] = {hv[rr].x, hv[rr].y, hv[rr].z, hv[rr].w};
#pragma unroll
            for (int kk = 0; kk < 4; ++kk) {
                acc[rr][0] += hk[kk] * wv[kk].x;
                acc[rr][1] += hk[kk] * wv[kk].y;
                acc[rr][2] += hk[kk] * wv[kk].z;
                acc[rr][3] += hk[kk] * wv[kk].w;
            }
        }
    }
    int rloc = r0 + rg * 2;
    int b = rloc >> 11;
    int j = rloc & (NN - 1);  // even
#pragma unroll
    for (int cc = 0; cc < 4; ++cc) {
        float v0 = acc[0][cc], v1 = acc[1][cc];
        short h0 = f2bf(v0), h1 = f2bf(v1);
        short l0 = f2bf(v0 - bf2f(h0)), l1 = f2bf(v1 - bf2f(h1));
        size_t off = (size_t)(b * FF + f4 + cc) * NP + j;
        *(short2*)(WhHiT + off) = make_short2(h0, h1);
        *(short2*)(WhLoT + off) = make_short2(l0, l1);
    }
}

// ---------------------------------------------------------------------------
// k_attn v12 "fo-quarter / 1024 blocks" (resubmit; round-8 bench was an
// infra failure, theory untested): v10 was latency-bound at 16 waves/CU --
// NOT by resources but by GRID (512 blocks = 2/CU exactly). v11's fix
// (1024-thr + waves_per_eu(8,8)) made the allocator clamp to 32 VGPR ->
// 700MB scratch traffic. v12 doubles TLP the safe way: split each
// (b,tile) into 4 fo-quarters (32 fo) -> 1024 blocks x 512 thr = 4
// blocks/CU = 32 waves/CU = 8/SIMD. Row softmax stays block-local (each
// block recomputes its rows' EV sums; EV x2 vs v10, ~+2us VALU, cheap).
// Per wave: 8 j-steps, 2 ni x 2 mi = 4 accs, 2 B-pairs/step -> live set
// ~60 VGPR, pinned <=64 via __launch_bounds__(512, 8) (8 waves/EU min).
// Merge: 4KB images, 2-round tree through 4 buffers, LDS 17.5KB.
// Same proven per-step body (EV-in-reg + direct-from-L2 B) as v10.
// ---------------------------------------------------------------------------
#define EV(f2v, f1v, wv, bi) ({ float _t = (f1v) + (f2v); float _x = fmaxf(_t, ALPHA * _t); \
    __expf(_x - SHIFT_C) * (float)(((wv) >> (bi)) & 1u); })

__global__ __launch_bounds__(512, 8)
void k_attn(const short* __restrict__ WhHiT,
            const short* __restrict__ WhLoT,
            const u32* __restrict__ adjp,
            const float* __restrict__ f1,
            const float* __restrict__ f2,
            float* __restrict__ out) {
    __shared__ __align__(16) char lds[17536];  // 4 x 4KB merge bufs + row_ps 1KB + row_inv 128B
    float* row_ps = (float*)(lds + 16384);     // [8][32]
    float* row_inv = (float*)(lds + 17408);    // [32]

    int tid = threadIdx.x;
    int w = tid >> 6, lane = tid & 63;         // w 0..7
    int blk = blockIdx.x;                      // 1024 = 4 b x 64 tile x 4 qt
    int b = blk >> 8;
    int tile = (blk >> 2) & 63;
    int qt = blk & 3;
    int i0 = tile * 32;

    int r_c = lane & 15, kg = lane >> 4;

    const float* f2b = f2 + b * NN;
    float f10 = f1[b * NN + i0 + r_c];        // mi=0 row
    float f11 = f1[b * NN + i0 + 16 + r_c];   // mi=1 row
    const u32* ap0 = adjp + (size_t)(i0 + r_c) * 64;
    const u32* ap1 = adjp + (size_t)(i0 + 16 + r_c) * 64;

    // B-fragment row pointers (hi); lo at constant element delta
    const ptrdiff_t dLo = (ptrdiff_t)BB * FF * NP;
    int s0 = w * 8;  // this wave's 8 contiguous j-steps
    const short* pB0 = WhHiT + (size_t)(b * FF + qt * 32 + 0 * 16 + r_c) * NP + s0 * 32 + kg * 8;
    const short* pB1 = WhHiT + (size_t)(b * FF + qt * 32 + 1 * 16 + r_c) * NP + s0 * 32 + kg * 8;

    f32x4 acc0_0 = {0,0,0,0}, acc0_1 = {0,0,0,0};   // acc{ni}_{mi}
    f32x4 acc1_0 = {0,0,0,0}, acc1_1 = {0,0,0,0};
    float sp0 = 0.f, sp1 = 0.f;

#pragma unroll 1
    for (int s8 = 0; s8 < 8; ++s8) {
        int s = s0 + s8;
        // scalars for EV
        float4 q0 = *(const float4*)(f2b + s * 32 + kg * 8);
        float4 q1 = *(const float4*)(f2b + s * 32 + kg * 8 + 4);
        u32 w0 = ap0[s], w1 = ap1[s];
        // B loads for this step (4 x 16B; in flight during EV compute)
        bf16x8 bh0 = *(const bf16x8*)(pB0); bf16x8 bl0 = *(const bf16x8*)(pB0 + dLo);
        bf16x8 bh1 = *(const bf16x8*)(pB1); bf16x8 bl1 = *(const bf16x8*)(pB1 + dLo);

        // in-register A fragments: lane holds rows r_c (mi=0), 16+r_c (mi=1),
        // k-elements j = s*32 + kg*8 + e  (bit kg*8+e of adjp word s)
        union { u32 u[4]; bf16x8 v; } A0, A1;
        int bb = kg * 8;
        {
            float pa, pb;
            pa = EV(q0.x, f10, w0, bb + 0); pb = EV(q0.y, f10, w0, bb + 1);
            sp0 += pa + pb;
            asm("v_cvt_pk_bf16_f32 %0, %1, %2" : "=v"(A0.u[0]) : "v"(pa), "v"(pb));
            pa = EV(q0.z, f10, w0, bb + 2); pb = EV(q0.w, f10, w0, bb + 3);
            sp0 += pa + pb;
            asm("v_cvt_pk_bf16_f32 %0, %1, %2" : "=v"(A0.u[1]) : "v"(pa), "v"(pb));
            pa = EV(q1.x, f10, w0, bb + 4); pb = EV(q1.y, f10, w0, bb + 5);
            sp0 += pa + pb;
            asm("v_cvt_pk_bf16_f32 %0, %1, %2" : "=v"(A0.u[2]) : "v"(pa), "v"(pb));
            pa = EV(q1.z, f10, w0, bb + 6); pb = EV(q1.w, f10, w0, bb + 7);
            sp0 += pa + pb;
            asm("v_cvt_pk_bf16_f32 %0, %1, %2" : "=v"(A0.u[3]) : "v"(pa), "v"(pb));

            pa = EV(q0.x, f11, w1, bb + 0); pb = EV(q0.y, f11, w1, bb + 1);
            sp1 += pa + pb;
            asm("v_cvt_pk_bf16_f32 %0, %1, %2" : "=v"(A1.u[0]) : "v"(pa), "v"(pb));
            pa = EV(q0.z, f11, w1, bb + 2); pb = EV(q0.w, f11, w1, bb + 3);
            sp1 += pa + pb;
            asm("v_cvt_pk_bf16_f32 %0, %1, %2" : "=v"(A1.u[1]) : "v"(pa), "v"(pb));
            pa = EV(q1.x, f11, w1, bb + 4); pb = EV(q1.y, f11, w1, bb + 5);
            sp1 += pa + pb;
            asm("v_cvt_pk_bf16_f32 %0, %1, %2" : "=v"(A1.u[2]) : "v"(pa), "v"(pb));
            pa = EV(q1.z, f11, w1, bb + 6); pb = EV(q1.w, f11, w1, bb + 7);
            sp1 += pa + pb;
            asm("v_cvt_pk_bf16_f32 %0, %1, %2" : "=v"(A1.u[3]) : "v"(pa), "v"(pb));
        }

        // 8 MFMA: out = A{mi} x (Bhi+Blo){ni}, accumulate per (ni,mi)
        acc0_0 = __builtin_amdgcn_mfma_f32_16x16x32_bf16(A0.v, bh0, acc0_0, 0, 0, 0);
        acc0_0 = __builtin_amdgcn_mfma_f32_16x16x32_bf16(A0.v, bl0, acc0_0, 0, 0, 0);
        acc0_1 = __builtin_amdgcn_mfma_f32_16x16x32_bf16(A1.v, bh0, acc0_1, 0, 0, 0);
        acc0_1 = __builtin_amdgcn_mfma_f32_16x16x32_bf16(A1.v, bl0, acc0_1, 0, 0, 0);
        acc1_0 = __builtin_amdgcn_mfma_f32_16x16x32_bf16(A0.v, bh1, acc1_0, 0, 0, 0);
        acc1_0 = __builtin_amdgcn_mfma_f32_16x16x32_bf16(A0.v, bl1, acc1_0, 0, 0, 0);
        acc1_1 = __builtin_amdgcn_mfma_f32_16x16x32_bf16(A1.v, bh1, acc1_1, 0, 0, 0);
        acc1_1 = __builtin_amdgcn_mfma_f32_16x16x32_bf16(A1.v, bl1, acc1_1, 0, 0, 0);

        pB0 += 32; pB1 += 32;
    }

    // ---- epilogue: 2-round tree merge of 8 partial 32x32 images via 4 bufs ----
    sp0 += __shfl_xor(sp0, 16, 64); sp0 += __shfl_xor(sp0, 32, 64);
    sp1 += __shfl_xor(sp1, 16, 64); sp1 += __shfl_xor(sp1, 32, 64);
    if (lane < 16) {
        row_ps[w * 32 + lane] = sp0;
        row_ps[w * 32 + 16 + lane] = sp1;
    }
    // round A: waves 0-3 write their partial image (col-major, XOR-swizzled)
    if (w < 4) {
        char* img = lds + w * 4096;
#define STACC(NI, MI, A) { int ch = (((NI)*16 + r_c) * 8 + (MI)*4 + kg) ^ (r_c & 7); \
                           *(f32x4*)(img + ch * 16) = (A); }
        STACC(0, 0, acc0_0) STACC(0, 1, acc0_1)
        STACC(1, 0, acc1_0) STACC(1, 1, acc1_1)
#undef STACC
    }
    __syncthreads();
    // round B: waves 4-7 RMW-add into buffer (w-4); wave0 lanes<32 do row_inv
    if (w >= 4) {
        char* img = lds + (w - 4) * 4096;
#define MRGACC(NI, MI, A) { int ch = (((NI)*16 + r_c) * 8 + (MI)*4 + kg) ^ (r_c & 7); \
                            f32x4* p = (f32x4*)(img + ch * 16); *p = *p + (A); }
        MRGACC(0, 0, acc0_0) MRGACC(0, 1, acc0_1)
        MRGACC(1, 0, acc1_0) MRGACC(1, 1, acc1_1)
#undef MRGACC
    } else if (tid < 32) {
        float t = 0.f;
#pragma unroll
        for (int ww = 0; ww < 8; ++ww) t += row_ps[ww * 32 + tid];
        row_inv[tid] = 1.0f / t;
    }
    __syncthreads();

    // final: merge 4 buffers + normalize + store. wave w, lanes<32:
    // cols qt*32 + w*4 + (lane>>3), rows (lane&7)*4..+3
    if (lane < 32) {
        int colg = w * 4 + (lane >> 3);     // 0..31 within quarter
        int rq = lane & 7;
        int ch = (colg * 8 + rq) ^ (colg & 7);
        f32x4 v = {0, 0, 0, 0};
#pragma unroll
        for (int im = 0; im < 4; ++im)
            v += *(const f32x4*)(lds + im * 4096 + ch * 16);
        f32x4 rinv = *(const f32x4*)((char*)row_inv + rq * 16);
        float* ob = out + ((size_t)b * NN + i0 + rq * 4) * FF + qt * 32 + colg;
#pragma unroll
        for (int q = 0; q < 4; ++q)
            ob[(size_t)q * FF] = v[q] * rinv[q];
    }
}

// ---------------------------------------------------------------------------
extern "C" void kernel_launch(void* const* d_in, const int* in_sizes, int n_in,
                              void* d_out, int out_size, void* d_ws, size_t ws_size,
                              hipStream_t stream) {
    const float* h   = (const float*)d_in[0];
    const int*   adj = (const int*)d_in[1];
    const float* W   = (const float*)d_in[2];
    const float* a   = (const float*)d_in[3];
    float* out = (float*)d_out;

    short* WhHiT = (short*)d_ws;                          // 2.13 MB
    short* WhLoT = WhHiT + (size_t)BB * FF * NP;          // 2.13 MB
    float* f1 = (float*)(WhLoT + (size_t)BB * FF * NP);   // 32 KB
    float* f2 = f1 + (size_t)BB * NN;                     // 32 KB
    u32* adjp = (u32*)(f2 + (size_t)BB * NN);             // 512 KB (total ~4.83 MB, proven)

    k_wh<<<(BB * NN) / 16, 256, 0, stream>>>(h, W, a, adj, WhHiT, WhLoT, f1, f2, adjp);
    k_attn<<<1024, 512, 0, stream>>>(WhHiT, WhLoT, adjp, f1, f2, out);
}

// Round 10
// 147.641 us; speedup vs baseline: 1.7728x; 1.6360x over previous
//
#include <hip/hip_runtime.h>

#define BB 4
#define NN 2048
#define FF 128
#define NP 2176  // padded WhT row stride (shorts)
#define ALPHA 0.2f
#define SHIFT_C 16.0f  // exp(x-16): x=LR(f1+f2) bounded ~|10|; masked -> p=0 via bit-multiply

typedef short bf16x8 __attribute__((ext_vector_type(8)));
typedef float f32x4 __attribute__((ext_vector_type(4)));
typedef unsigned u32;

__device__ inline short f2bf(float f) {  // RNE float -> bf16 bits
    union { float f; unsigned u; } v; v.f = f;
    unsigned r = (v.u + 0x7FFFu + ((v.u >> 16) & 1u)) >> 16;
    return (short)r;
}
__device__ inline float bf2f(short s) {
    union { float f; unsigned u; } v;
    v.u = ((unsigned)(unsigned short)s) << 16;
    return v.f;
}

// async 16B global->LDS (gfx950); HW writes lds_base + lane*16; global addr per-lane
__device__ inline void cp16(const void* g, void* l) {
    __builtin_amdgcn_global_load_lds(
        (const __attribute__((address_space(1))) u32*)g,
        (__attribute__((address_space(3))) u32*)l, 16, 0, 0);
}

// ---------------------------------------------------------------------------
// k_wh: unchanged (passed).
// ---------------------------------------------------------------------------
__global__ __launch_bounds__(256) void k_wh(const float* __restrict__ h,
                                            const float* __restrict__ W,
                                            const float* __restrict__ a,
                                            const int* __restrict__ adj,
                                            short* __restrict__ WhHiT,
                                            short* __restrict__ WhLoT,
                                            float* __restrict__ f1,
                                            float* __restrict__ f2,
                                            u32* __restrict__ adjp) {
    __shared__ float Wa[2 * FF];
    __shared__ float hs[16 * 128];  // 8 KB
    int tid = threadIdx.x;
    int r0 = blockIdx.x * 16;

    {
        int fin = tid & 127;
        const float* av = (tid < 128) ? a : (a + FF);
        const float* wr = W + (size_t)fin * FF;
        float s = 0.f;
        for (int o = 0; o < FF; o += 4) {
            float4 wv = *(const float4*)(wr + o);
            float4 avv = *(const float4*)(av + o);
            s += wv.x * avv.x + wv.y * avv.y + wv.z * avv.z + wv.w * avv.w;
        }
        Wa[(tid < 128 ? 0 : FF) + fin] = s;
    }
    {
        const float4* src = (const float4*)(h + (size_t)r0 * FF);
        float4* dst = (float4*)hs;
        dst[tid] = src[tid];
        dst[256 + tid] = src[256 + tid];
    }
    // de-serialized adj pack: 512 blocks * 256 thr = 131072 = 2048 rows * 64 words
    {
        int g = blockIdx.x * 256 + tid;
        int row = g >> 6, wd = g & 63;
        const int4* ar = (const int4*)(adj + (size_t)row * NN + wd * 32);
        u32 word = 0;
#pragma unroll
        for (int q = 0; q < 8; ++q) {
            int4 v = ar[q];
            word |= (u32)(v.x > 0) << (q * 4);
            word |= (u32)(v.y > 0) << (q * 4 + 1);
            word |= (u32)(v.z > 0) << (q * 4 + 2);
            word |= (u32)(v.w > 0) << (q * 4 + 3);
        }
        adjp[row * 64 + wd] = word;
    }
    __syncthreads();

    {
        int w = tid >> 6, lane = tid & 63;
        float wa1_0 = Wa[lane], wa1_1 = Wa[lane + 64];
        float wa2_0 = Wa[FF + lane], wa2_1 = Wa[FF + lane + 64];
        for (int rr = 0; rr < 4; ++rr) {
            int rloc = w * 4 + rr;
            int row = r0 + rloc;
            float x0 = hs[rloc * FF + lane], x1 = hs[rloc * FF + lane + 64];
            float s1 = x0 * wa1_0 + x1 * wa1_1;
            float s2 = x0 * wa2_0 + x1 * wa2_1;
#pragma unroll
            for (int m = 32; m >= 1; m >>= 1) {
                s1 += __shfl_xor(s1, m, 64);
                s2 += __shfl_xor(s2, m, 64);
            }
            if (lane == 0) { f1[row] = s1; f2[row] = s2; }
        }
    }

    int f4 = (tid & 31) * 4;
    int rg = tid >> 5;  // 0..7
    float acc[2][4];
#pragma unroll
    for (int rr = 0; rr < 2; ++rr)
#pragma unroll
        for (int cc = 0; cc < 4; ++cc) acc[rr][cc] = 0.f;

    for (int k0 = 0; k0 < FF; k0 += 4) {
        float4 wv[4];
#pragma unroll
        for (int kk = 0; kk < 4; ++kk)
            wv[kk] = *(const float4*)(W + (size_t)(k0 + kk) * FF + f4);
        float4 hv[2];
#pragma unroll
        for (int rr = 0; rr < 2; ++rr)
            hv[rr] = *(const float4*)(hs + (rg * 2 + rr) * FF + k0);
#pragma unroll
        for (int rr = 0; rr < 2; ++rr) {
            float hk[4] = {hv[rr].x, hv[rr].y, hv[rr].z, hv[rr].w};
#pragma unroll
            for (int kk = 0; kk < 4; ++kk) {
                acc[rr][0] += hk[kk] * wv[kk].x;
                acc[rr][1] += hk[kk] * wv[kk].y;
                acc[rr][2] += hk[kk] * wv[kk].z;
                acc[rr][3] += hk[kk] * wv[kk].w;
            }
        }
    }
    int rloc = r0 + rg * 2;
    int b = rloc >> 11;
    int j = rloc & (NN - 1);  // even
#pragma unroll
    for (int cc = 0; cc < 4; ++cc) {
        float v0 = acc[0][cc], v1 = acc[1][cc];
        short h0 = f2bf(v0), h1 = f2bf(v1);
        short l0 = f2bf(v0 - bf2f(h0)), l1 = f2bf(v1 - bf2f(h1));
        size_t off = (size_t)(b * FF + f4 + cc) * NP + j;
        *(short2*)(WhHiT + off) = make_short2(h0, h1);
        *(short2*)(WhLoT + off) = make_short2(l0, l1);
    }
}

// ---------------------------------------------------------------------------
// k_attn v13 "async bounce-buffer": v12's validated geometry (1024 blocks x
// 512 thr, fo-quarters, passed R9) with the B path switched from VGPR loads
// to ZERO-VGPR cp16 staging. Diagnosis chain: v10 = latency-bound (64-reg
// schedule serialized B loads, ~2 outstanding); v11/v12 proved any
// 8-waves/EU request clamps arch VGPRs to 32 (unified-file split) -> spill.
// So 4 waves/SIMD is the budget; latency must be hidden ASYNC. v13:
// per-wave private 8KB LDS dbuf (two 4KB step-bufs); per iter:
//   [4 cp16 (s+1)->buf^1] |SB| [4 scalar prefetch (s+1)] |SB| EV(s)
//   vmcnt(8) (batch s is OLDER than the 8 newest -> landed) |SB|
//   ds_read x4 from buf (lane reads back its own 16B slot) -> 8 MFMA
// No cross-wave barrier in the loop; vmcnt is in-order (m135). EV's ~350cy
// covers L2 latency. Live set ~70 VGPR < 128 (waves_per_eu(4,4), the
// v10-proven no-spill combo). LDS: 8x8KB staging + row_ps/inv = 65.1KB,
// 2 blocks/CU; merge bufs OVERLAY staging bytes 0-16K after a draining
// __syncthreads (added at epilogue start -- cp16s must land first).
// ---------------------------------------------------------------------------
#define EV(f2v, f1v, wv, bi) ({ float _t = (f1v) + (f2v); float _x = fmaxf(_t, ALPHA * _t); \
    __expf(_x - SHIFT_C) * (float)(((wv) >> (bi)) & 1u); })

__global__ __launch_bounds__(512) __attribute__((amdgpu_waves_per_eu(4, 4)))
void k_attn(const short* __restrict__ WhHiT,
            const short* __restrict__ WhLoT,
            const u32* __restrict__ adjp,
            const float* __restrict__ f1,
            const float* __restrict__ f2,
            float* __restrict__ out) {
    __shared__ __align__(16) char lds[66688];
    // staging: wave w -> lds + w*8192 (two 4KB step-bufs); merge bufs overlay 0..16K post-loop
    float* row_ps = (float*)(lds + 65536);     // [8][32]
    float* row_inv = (float*)(lds + 66560);    // [32]

    int tid = threadIdx.x;
    int w = tid >> 6, lane = tid & 63;         // w 0..7
    int blk = blockIdx.x;                      // 1024 = 4 b x 64 tile x 4 qt
    int b = blk >> 8;
    int tile = (blk >> 2) & 63;
    int qt = blk & 3;
    int i0 = tile * 32;

    int r_c = lane & 15, kg = lane >> 4;

    const float* f2b = f2 + b * NN;
    float f10 = f1[b * NN + i0 + r_c];        // mi=0 row
    float f11 = f1[b * NN + i0 + 16 + r_c];   // mi=1 row
    const u32* ap0 = adjp + (size_t)(i0 + r_c) * 64;
    const u32* ap1 = adjp + (size_t)(i0 + 16 + r_c) * 64;

    const ptrdiff_t dLo = (ptrdiff_t)BB * FF * NP;
    int s0 = w * 8;  // this wave's 8 contiguous j-steps
    const short* pB0 = WhHiT + (size_t)(b * FF + qt * 32 + 0 * 16 + r_c) * NP + s0 * 32 + kg * 8;
    const short* pB1 = WhHiT + (size_t)(b * FF + qt * 32 + 1 * 16 + r_c) * NP + s0 * 32 + kg * 8;

    char* stg = lds + w * 8192;  // wave-private dbuf

    f32x4 acc0_0 = {0,0,0,0}, acc0_1 = {0,0,0,0};   // acc{ni}_{mi}
    f32x4 acc1_0 = {0,0,0,0}, acc1_1 = {0,0,0,0};
    float sp0 = 0.f, sp1 = 0.f;

    // ---- prologue: stage step s0 -> buf0; load step-s0 scalars ----
    cp16(pB0, stg);                      // ni0 hi
    cp16(pB0 + dLo, stg + 1024);         // ni0 lo
    cp16(pB1, stg + 2048);               // ni1 hi
    cp16(pB1 + dLo, stg + 3072);         // ni1 lo
    __builtin_amdgcn_sched_barrier(0);
    float4 q0 = *(const float4*)(f2b + s0 * 32 + kg * 8);
    float4 q1 = *(const float4*)(f2b + s0 * 32 + kg * 8 + 4);
    u32 w0 = ap0[s0], w1 = ap1[s0];
    __builtin_amdgcn_sched_barrier(0);

#pragma unroll 1
    for (int s8 = 0; s8 < 8; ++s8) {
        int cur = s8 & 1;
        int snw = (s8 + 1) & 7;            // next step (wrapped; wrap unused)
        int sn = s0 + snw;
        // stage step s+1 -> other buf (4 cp16, zero VGPR)
        {
            char* nb = stg + (cur ^ 1) * 4096;
            const short* nB0 = pB0 + snw * 32;
            const short* nB1 = pB1 + snw * 32;
            cp16(nB0, nb);
            cp16(nB0 + dLo, nb + 1024);
            cp16(nB1, nb + 2048);
            cp16(nB1 + dLo, nb + 3072);
        }
        __builtin_amdgcn_sched_barrier(0);
        // prefetch step-(s+1) scalars (issued AFTER the cp16 batch: in-order
        // vmcnt means compiler's wait for these also retires this batch later)
        float4 nq0 = *(const float4*)(f2b + sn * 32 + kg * 8);
        float4 nq1 = *(const float4*)(f2b + sn * 32 + kg * 8 + 4);
        u32 nw0 = ap0[sn], nw1 = ap1[sn];
        __builtin_amdgcn_sched_barrier(0);

        // EV(s) from current scalars -> in-register A fragments
        union { u32 u[4]; bf16x8 v; } A0, A1;
        int bb = kg * 8;
        {
            float pa, pb;
            pa = EV(q0.x, f10, w0, bb + 0); pb = EV(q0.y, f10, w0, bb + 1);
            sp0 += pa + pb;
            asm("v_cvt_pk_bf16_f32 %0, %1, %2" : "=v"(A0.u[0]) : "v"(pa), "v"(pb));
            pa = EV(q0.z, f10, w0, bb + 2); pb = EV(q0.w, f10, w0, bb + 3);
            sp0 += pa + pb;
            asm("v_cvt_pk_bf16_f32 %0, %1, %2" : "=v"(A0.u[1]) : "v"(pa), "v"(pb));
            pa = EV(q1.x, f10, w0, bb + 4); pb = EV(q1.y, f10, w0, bb + 5);
            sp0 += pa + pb;
            asm("v_cvt_pk_bf16_f32 %0, %1, %2" : "=v"(A0.u[2]) : "v"(pa), "v"(pb));
            pa = EV(q1.z, f10, w0, bb + 6); pb = EV(q1.w, f10, w0, bb + 7);
            sp0 += pa + pb;
            asm("v_cvt_pk_bf16_f32 %0, %1, %2" : "=v"(A0.u[3]) : "v"(pa), "v"(pb));

            pa = EV(q0.x, f11, w1, bb + 0); pb = EV(q0.y, f11, w1, bb + 1);
            sp1 += pa + pb;
            asm("v_cvt_pk_bf16_f32 %0, %1, %2" : "=v"(A1.u[0]) : "v"(pa), "v"(pb));
            pa = EV(q0.z, f11, w1, bb + 2); pb = EV(q0.w, f11, w1, bb + 3);
            sp1 += pa + pb;
            asm("v_cvt_pk_bf16_f32 %0, %1, %2" : "=v"(A1.u[1]) : "v"(pa), "v"(pb));
            pa = EV(q1.x, f11, w1, bb + 4); pb = EV(q1.y, f11, w1, bb + 5);
            sp1 += pa + pb;
            asm("v_cvt_pk_bf16_f32 %0, %1, %2" : "=v"(A1.u[2]) : "v"(pa), "v"(pb));
            pa = EV(q1.z, f11, w1, bb + 6); pb = EV(q1.w, f11, w1, bb + 7);
            sp1 += pa + pb;
            asm("v_cvt_pk_bf16_f32 %0, %1, %2" : "=v"(A1.u[3]) : "v"(pa), "v"(pb));
        }

        // batch s landed: everything except the 8 newest (4 cp16 + 4 scalars of s+1)
        asm volatile("s_waitcnt vmcnt(8)" ::: "memory");
        __builtin_amdgcn_sched_barrier(0);

        // read back this wave's staged fragments (lane reads its own 16B slot)
        char* buf = stg + cur * 4096;
        bf16x8 bh0 = *(const bf16x8*)(buf + lane * 16);
        bf16x8 bl0 = *(const bf16x8*)(buf + 1024 + lane * 16);
        bf16x8 bh1 = *(const bf16x8*)(buf + 2048 + lane * 16);
        bf16x8 bl1 = *(const bf16x8*)(buf + 3072 + lane * 16);

        // 8 MFMA: out = A{mi} x (Bhi+Blo){ni}
        acc0_0 = __builtin_amdgcn_mfma_f32_16x16x32_bf16(A0.v, bh0, acc0_0, 0, 0, 0);
        acc0_0 = __builtin_amdgcn_mfma_f32_16x16x32_bf16(A0.v, bl0, acc0_0, 0, 0, 0);
        acc0_1 = __builtin_amdgcn_mfma_f32_16x16x32_bf16(A1.v, bh0, acc0_1, 0, 0, 0);
        acc0_1 = __builtin_amdgcn_mfma_f32_16x16x32_bf16(A1.v, bl0, acc0_1, 0, 0, 0);
        acc1_0 = __builtin_amdgcn_mfma_f32_16x16x32_bf16(A0.v, bh1, acc1_0, 0, 0, 0);
        acc1_0 = __builtin_amdgcn_mfma_f32_16x16x32_bf16(A0.v, bl1, acc1_0, 0, 0, 0);
        acc1_1 = __builtin_amdgcn_mfma_f32_16x16x32_bf16(A1.v, bh1, acc1_1, 0, 0, 0);
        acc1_1 = __builtin_amdgcn_mfma_f32_16x16x32_bf16(A1.v, bl1, acc1_1, 0, 0, 0);

        // roll scalars
        q0 = nq0; q1 = nq1; w0 = nw0; w1 = nw1;
        __builtin_amdgcn_sched_barrier(0);
    }

    // ---- epilogue (v12-validated, + draining barrier before merge overlay) ----
    sp0 += __shfl_xor(sp0, 16, 64); sp0 += __shfl_xor(sp0, 32, 64);
    sp1 += __shfl_xor(sp1, 16, 64); sp1 += __shfl_xor(sp1, 32, 64);
    if (lane < 16) {
        row_ps[w * 32 + lane] = sp0;
        row_ps[w * 32 + 16 + lane] = sp1;
    }
    __syncthreads();  // drains all in-flight cp16 (vmcnt 0) -> staging reusable
    // round A: waves 0-3 write partial image (col-major, XOR-swizzled) into overlay
    if (w < 4) {
        char* img = lds + w * 4096;
#define STACC(NI, MI, A) { int ch = (((NI)*16 + r_c) * 8 + (MI)*4 + kg) ^ (r_c & 7); \
                           *(f32x4*)(img + ch * 16) = (A); }
        STACC(0, 0, acc0_0) STACC(0, 1, acc0_1)
        STACC(1, 0, acc1_0) STACC(1, 1, acc1_1)
#undef STACC
    }
    __syncthreads();
    // round B: waves 4-7 RMW-add into buffer (w-4); wave0 lanes<32 do row_inv
    if (w >= 4) {
        char* img = lds + (w - 4) * 4096;
#define MRGACC(NI, MI, A) { int ch = (((NI)*16 + r_c) * 8 + (MI)*4 + kg) ^ (r_c & 7); \
                            f32x4* p = (f32x4*)(img + ch * 16); *p = *p + (A); }
        MRGACC(0, 0, acc0_0) MRGACC(0, 1, acc0_1)
        MRGACC(1, 0, acc1_0) MRGACC(1, 1, acc1_1)
#undef MRGACC
    } else if (tid < 32) {
        float t = 0.f;
#pragma unroll
        for (int ww = 0; ww < 8; ++ww) t += row_ps[ww * 32 + tid];
        row_inv[tid] = 1.0f / t;
    }
    __syncthreads();

    // final: merge 4 buffers + normalize + store. wave w, lanes<32:
    // cols qt*32 + w*4 + (lane>>3), rows (lane&7)*4..+3
    if (lane < 32) {
        int colg = w * 4 + (lane >> 3);     // 0..31 within quarter
        int rq = lane & 7;
        int ch = (colg * 8 + rq) ^ (colg & 7);
        f32x4 v = {0, 0, 0, 0};
#pragma unroll
        for (int im = 0; im < 4; ++im)
            v += *(const f32x4*)(lds + im * 4096 + ch * 16);
        f32x4 rinv = *(const f32x4*)((char*)row_inv + rq * 16);
        float* ob = out + ((size_t)b * NN + i0 + rq * 4) * FF + qt * 32 + colg;
#pragma unroll
        for (int q = 0; q < 4; ++q)
            ob[(size_t)q * FF] = v[q] * rinv[q];
    }
}

// ---------------------------------------------------------------------------
extern "C" void kernel_launch(void* const* d_in, const int* in_sizes, int n_in,
                              void* d_out, int out_size, void* d_ws, size_t ws_size,
                              hipStream_t stream) {
    const float* h   = (const float*)d_in[0];
    const int*   adj = (const int*)d_in[1];
    const float* W   = (const float*)d_in[2];
    const float* a   = (const float*)d_in[3];
    float* out = (float*)d_out;

    short* WhHiT = (short*)d_ws;                          // 2.13 MB
    short* WhLoT = WhHiT + (size_t)BB * FF * NP;          // 2.13 MB
    float* f1 = (float*)(WhLoT + (size_t)BB * FF * NP);   // 32 KB
    float* f2 = f1 + (size_t)BB * NN;                     // 32 KB
    u32* adjp = (u32*)(f2 + (size_t)BB * NN);             // 512 KB (total ~4.83 MB, proven)

    k_wh<<<(BB * NN) / 16, 256, 0, stream>>>(h, W, a, adj, WhHiT, WhLoT, f1, f2, adjp);
    k_attn<<<1024, 512, 0, stream>>>(WhHiT, WhLoT, adjp, f1, f2, out);
}

// Round 11
// 129.303 us; speedup vs baseline: 2.0242x; 1.1418x over previous
//
#include <hip/hip_runtime.h>

#define BB 4
#define NN 2048
#define FF 128
#define NP 2176  // padded WhT row stride (shorts)
#define ALPHA 0.2f
#define SHIFT_C 16.0f  // exp(x-16): x=LR(f1+f2) bounded ~|10|; masked -> p=0 via bit-multiply

typedef short bf16x8 __attribute__((ext_vector_type(8)));
typedef float f32x4 __attribute__((ext_vector_type(4)));
typedef unsigned u32;

__device__ inline short f2bf(float f) {  // RNE float -> bf16 bits
    union { float f; unsigned u; } v; v.f = f;
    unsigned r = (v.u + 0x7FFFu + ((v.u >> 16) & 1u)) >> 16;
    return (short)r;
}
__device__ inline float bf2f(short s) {
    union { float f; unsigned u; } v;
    v.u = ((unsigned)(unsigned short)s) << 16;
    return v.f;
}

// ---------------------------------------------------------------------------
// k_wh v2: GEMM body unchanged (proven). STORE PATH REWRITTEN: the old
// epilogue wrote short2 (4B) at 4.3KB stride -- every lane its own cache
// line, ~1M 4B write transactions for 17.8MB of WhT (suspected 25-35us of
// the never-profiled k_wh). New epilogue: (1) barrier, (2) write the 16x128
// fp32 tile into LDS at row stride 132 (16B-aligned rows, conflict-light),
// (3) barrier, (4) thread (fo=tid>>1, jh=tid&1) reads 8 fp32 at stride 132
// (2 lanes/bank = free per m136), converts to hi/lo bf16, stores 16B (8
// consecutive j). Lane pairs form 32B segments -> ~8x fewer store instrs,
// 8x bytes/transaction.
// ---------------------------------------------------------------------------
__global__ __launch_bounds__(256) void k_wh(const float* __restrict__ h,
                                            const float* __restrict__ W,
                                            const float* __restrict__ a,
                                            const int* __restrict__ adj,
                                            short* __restrict__ WhHiT,
                                            short* __restrict__ WhLoT,
                                            float* __restrict__ f1,
                                            float* __restrict__ f2,
                                            u32* __restrict__ adjp) {
    __shared__ float Wa[2 * FF];
    __shared__ float hs[16 * 132];  // 8.25 KB: h-stage (16x128 used) then fp32 transpose tile (stride 132)
    int tid = threadIdx.x;
    int r0 = blockIdx.x * 16;

    {
        int fin = tid & 127;
        const float* av = (tid < 128) ? a : (a + FF);
        const float* wr = W + (size_t)fin * FF;
        float s = 0.f;
        for (int o = 0; o < FF; o += 4) {
            float4 wv = *(const float4*)(wr + o);
            float4 avv = *(const float4*)(av + o);
            s += wv.x * avv.x + wv.y * avv.y + wv.z * avv.z + wv.w * avv.w;
        }
        Wa[(tid < 128 ? 0 : FF) + fin] = s;
    }
    {
        const float4* src = (const float4*)(h + (size_t)r0 * FF);
        float4* dst = (float4*)hs;
        dst[tid] = src[tid];
        dst[256 + tid] = src[256 + tid];
    }
    // de-serialized adj pack: 512 blocks * 256 thr = 131072 = 2048 rows * 64 words
    {
        int g = blockIdx.x * 256 + tid;
        int row = g >> 6, wd = g & 63;
        const int4* ar = (const int4*)(adj + (size_t)row * NN + wd * 32);
        u32 word = 0;
#pragma unroll
        for (int q = 0; q < 8; ++q) {
            int4 v = ar[q];
            word |= (u32)(v.x > 0) << (q * 4);
            word |= (u32)(v.y > 0) << (q * 4 + 1);
            word |= (u32)(v.z > 0) << (q * 4 + 2);
            word |= (u32)(v.w > 0) << (q * 4 + 3);
        }
        adjp[row * 64 + wd] = word;
    }
    __syncthreads();

    {
        int w = tid >> 6, lane = tid & 63;
        float wa1_0 = Wa[lane], wa1_1 = Wa[lane + 64];
        float wa2_0 = Wa[FF + lane], wa2_1 = Wa[FF + lane + 64];
        for (int rr = 0; rr < 4; ++rr) {
            int rloc = w * 4 + rr;
            int row = r0 + rloc;
            float x0 = hs[rloc * FF + lane], x1 = hs[rloc * FF + lane + 64];
            float s1 = x0 * wa1_0 + x1 * wa1_1;
            float s2 = x0 * wa2_0 + x1 * wa2_1;
#pragma unroll
            for (int m = 32; m >= 1; m >>= 1) {
                s1 += __shfl_xor(s1, m, 64);
                s2 += __shfl_xor(s2, m, 64);
            }
            if (lane == 0) { f1[row] = s1; f2[row] = s2; }
        }
    }

    int f4 = (tid & 31) * 4;
    int rg = tid >> 5;  // 0..7
    float acc[2][4];
#pragma unroll
    for (int rr = 0; rr < 2; ++rr)
#pragma unroll
        for (int cc = 0; cc < 4; ++cc) acc[rr][cc] = 0.f;

    for (int k0 = 0; k0 < FF; k0 += 4) {
        float4 wv[4];
#pragma unroll
        for (int kk = 0; kk < 4; ++kk)
            wv[kk] = *(const float4*)(W + (size_t)(k0 + kk) * FF + f4);
        float4 hv[2];
#pragma unroll
        for (int rr = 0; rr < 2; ++rr)
            hv[rr] = *(const float4*)(hs + (rg * 2 + rr) * FF + k0);
#pragma unroll
        for (int rr = 0; rr < 2; ++rr) {
            float hk[4] = {hv[rr].x, hv[rr].y, hv[rr].z, hv[rr].w};
#pragma unroll
            for (int kk = 0; kk < 4; ++kk) {
                acc[rr][0] += hk[kk] * wv[kk].x;
                acc[rr][1] += hk[kk] * wv[kk].y;
                acc[rr][2] += hk[kk] * wv[kk].z;
                acc[rr][3] += hk[kk] * wv[kk].w;
            }
        }
    }

    // ---- NEW: LDS transpose + coalesced 16B stores ----
    __syncthreads();  // all GEMM reads of hs done
    {
#pragma unroll
        for (int rr = 0; rr < 2; ++rr)
            *(float4*)(hs + (rg * 2 + rr) * 132 + f4) =
                make_float4(acc[rr][0], acc[rr][1], acc[rr][2], acc[rr][3]);
    }
    __syncthreads();
    {
        int fo = tid >> 1, jh = tid & 1;
        bf16x8 hv_, lv_;
#pragma unroll
        for (int jj = 0; jj < 8; ++jj) {
            float v = hs[(jh * 8 + jj) * 132 + fo];
            short hh = f2bf(v);
            hv_[jj] = hh;
            lv_[jj] = f2bf(v - bf2f(hh));
        }
        int b = r0 >> 11;
        int j0 = (r0 & (NN - 1)) + jh * 8;
        size_t off = (size_t)(b * FF + fo) * NP + j0;
        *(bf16x8*)(WhHiT + off) = hv_;
        *(bf16x8*)(WhLoT + off) = lv_;
    }
}

// ---------------------------------------------------------------------------
// k_attn: REVERTED to v8 verbatim (round-3 kernel: best measured total,
// dur 129.2, passed). Wave-autonomous: each wave owns 8 complete j-steps,
// A-fragments computed in registers, B direct from L2-resident WhT, zero
// barriers in main loop. v9-v13 (fences / waves_per_eu pins / occupancy
// splits / bounce buffer) all landed 45-62us vs v8's ~42: every non-spill
// structure is latency-bound at 16 waves/CU, and the 8-waves/SIMD path
// needs <=64 unified regs vs this body's ~90-reg live set. v8 stands.
// ---------------------------------------------------------------------------
#define EV(f2v, f1v, wv, bi) ({ float _t = (f1v) + (f2v); float _x = fmaxf(_t, ALPHA * _t); \
    __expf(_x - SHIFT_C) * (float)(((wv) >> (bi)) & 1u); })

__global__ __launch_bounds__(512, 4) void k_attn(const short* __restrict__ WhHiT,
                                                 const short* __restrict__ WhLoT,
                                                 const u32* __restrict__ adjp,
                                                 const float* __restrict__ f1,
                                                 const float* __restrict__ f2,
                                                 float* __restrict__ out) {
    __shared__ __align__(16) char lds[66688];  // 8 x 8KB images + row_ps 1KB + row_inv 128B
    float* row_ps = (float*)(lds + 65536);     // [8][32]
    float* row_inv = (float*)(lds + 66560);    // [32]

    int tid = threadIdx.x;
    int w = tid >> 6, lane = tid & 63;
    int blk = blockIdx.x;
    int b = blk >> 7;
    int tile = (blk >> 1) & 63;
    int half = blk & 1;
    int i0 = tile * 32;

    int r_c = lane & 15, kg = lane >> 4;

    const float* f2b = f2 + b * NN;
    float f10 = f1[b * NN + i0 + r_c];        // mi=0 row
    float f11 = f1[b * NN + i0 + 16 + r_c];   // mi=1 row
    const u32* ap0 = adjp + (size_t)(i0 + r_c) * 64;
    const u32* ap1 = adjp + (size_t)(i0 + 16 + r_c) * 64;

    // B-fragment row pointers (hi); lo at constant element delta
    const ptrdiff_t dLo = (ptrdiff_t)BB * FF * NP;
    int s0 = w * 8;  // this wave's first step (contiguous 8 steps)
    const short* pB0 = WhHiT + (size_t)(b * FF + half * 64 + 0 * 16 + r_c) * NP + s0 * 32 + kg * 8;
    const short* pB1 = WhHiT + (size_t)(b * FF + half * 64 + 1 * 16 + r_c) * NP + s0 * 32 + kg * 8;
    const short* pB2 = WhHiT + (size_t)(b * FF + half * 64 + 2 * 16 + r_c) * NP + s0 * 32 + kg * 8;
    const short* pB3 = WhHiT + (size_t)(b * FF + half * 64 + 3 * 16 + r_c) * NP + s0 * 32 + kg * 8;

    f32x4 acc0_0 = {0,0,0,0}, acc0_1 = {0,0,0,0};
    f32x4 acc1_0 = {0,0,0,0}, acc1_1 = {0,0,0,0};
    f32x4 acc2_0 = {0,0,0,0}, acc2_1 = {0,0,0,0};
    f32x4 acc3_0 = {0,0,0,0}, acc3_1 = {0,0,0,0};
    float sp0 = 0.f, sp1 = 0.f;

    // prologue: scalars for step s0
    float4 q0 = *(const float4*)(f2b + s0 * 32 + kg * 8);
    float4 q1 = *(const float4*)(f2b + s0 * 32 + kg * 8 + 4);
    u32 w0 = ap0[s0], w1 = ap1[s0];

#pragma unroll
    for (int s8 = 0; s8 < 8; ++s8) {
        // B loads for this step (8 x 16B; consumed after ~350cy of e-compute)
        bf16x8 bh0 = *(const bf16x8*)(pB0); bf16x8 bl0 = *(const bf16x8*)(pB0 + dLo);
        bf16x8 bh1 = *(const bf16x8*)(pB1); bf16x8 bl1 = *(const bf16x8*)(pB1 + dLo);
        bf16x8 bh2 = *(const bf16x8*)(pB2); bf16x8 bl2 = *(const bf16x8*)(pB2 + dLo);
        bf16x8 bh3 = *(const bf16x8*)(pB3); bf16x8 bl3 = *(const bf16x8*)(pB3 + dLo);
        // prefetch next step's scalars (wrap harmless)
        int sn = (s0 + s8 + 1) & 63;
        float4 nq0 = *(const float4*)(f2b + sn * 32 + kg * 8);
        float4 nq1 = *(const float4*)(f2b + sn * 32 + kg * 8 + 4);
        u32 nw0 = ap0[sn], nw1 = ap1[sn];

        // in-register A fragments: lane holds rows r_c (mi=0), 16+r_c (mi=1),
        // k-elements j = s*32 + kg*8 + e  (bit kg*8+e of adjp word s)
        union { u32 u[4]; bf16x8 v; } A0, A1;
        int bb = kg * 8;
        {
            float pa, pb;
            pa = EV(q0.x, f10, w0, bb + 0); pb = EV(q0.y, f10, w0, bb + 1);
            sp0 += pa + pb;
            asm("v_cvt_pk_bf16_f32 %0, %1, %2" : "=v"(A0.u[0]) : "v"(pa), "v"(pb));
            pa = EV(q0.z, f10, w0, bb + 2); pb = EV(q0.w, f10, w0, bb + 3);
            sp0 += pa + pb;
            asm("v_cvt_pk_bf16_f32 %0, %1, %2" : "=v"(A0.u[1]) : "v"(pa), "v"(pb));
            pa = EV(q1.x, f10, w0, bb + 4); pb = EV(q1.y, f10, w0, bb + 5);
            sp0 += pa + pb;
            asm("v_cvt_pk_bf16_f32 %0, %1, %2" : "=v"(A0.u[2]) : "v"(pa), "v"(pb));
            pa = EV(q1.z, f10, w0, bb + 6); pb = EV(q1.w, f10, w0, bb + 7);
            sp0 += pa + pb;
            asm("v_cvt_pk_bf16_f32 %0, %1, %2" : "=v"(A0.u[3]) : "v"(pa), "v"(pb));

            pa = EV(q0.x, f11, w1, bb + 0); pb = EV(q0.y, f11, w1, bb + 1);
            sp1 += pa + pb;
            asm("v_cvt_pk_bf16_f32 %0, %1, %2" : "=v"(A1.u[0]) : "v"(pa), "v"(pb));
            pa = EV(q0.z, f11, w1, bb + 2); pb = EV(q0.w, f11, w1, bb + 3);
            sp1 += pa + pb;
            asm("v_cvt_pk_bf16_f32 %0, %1, %2" : "=v"(A1.u[1]) : "v"(pa), "v"(pb));
            pa = EV(q1.x, f11, w1, bb + 4); pb = EV(q1.y, f11, w1, bb + 5);
            sp1 += pa + pb;
            asm("v_cvt_pk_bf16_f32 %0, %1, %2" : "=v"(A1.u[2]) : "v"(pa), "v"(pb));
            pa = EV(q1.z, f11, w1, bb + 6); pb = EV(q1.w, f11, w1, bb + 7);
            sp1 += pa + pb;
            asm("v_cvt_pk_bf16_f32 %0, %1, %2" : "=v"(A1.u[3]) : "v"(pa), "v"(pb));
        }

        // 8 MFMA: out = A x (Bhi + Blo), both halves into the same acc
        acc0_0 = __builtin_amdgcn_mfma_f32_16x16x32_bf16(A0.v, bh0, acc0_0, 0, 0, 0);
        acc0_0 = __builtin_amdgcn_mfma_f32_16x16x32_bf16(A0.v, bl0, acc0_0, 0, 0, 0);
        acc0_1 = __builtin_amdgcn_mfma_f32_16x16x32_bf16(A1.v, bh0, acc0_1, 0, 0, 0);
        acc0_1 = __builtin_amdgcn_mfma_f32_16x16x32_bf16(A1.v, bl0, acc0_1, 0, 0, 0);
        acc1_0 = __builtin_amdgcn_mfma_f32_16x16x32_bf16(A0.v, bh1, acc1_0, 0, 0, 0);
        acc1_0 = __builtin_amdgcn_mfma_f32_16x16x32_bf16(A0.v, bl1, acc1_0, 0, 0, 0);
        acc1_1 = __builtin_amdgcn_mfma_f32_16x16x32_bf16(A1.v, bh1, acc1_1, 0, 0, 0);
        acc1_1 = __builtin_amdgcn_mfma_f32_16x16x32_bf16(A1.v, bl1, acc1_1, 0, 0, 0);
        acc2_0 = __builtin_amdgcn_mfma_f32_16x16x32_bf16(A0.v, bh2, acc2_0, 0, 0, 0);
        acc2_0 = __builtin_amdgcn_mfma_f32_16x16x32_bf16(A0.v, bl2, acc2_0, 0, 0, 0);
        acc2_1 = __builtin_amdgcn_mfma_f32_16x16x32_bf16(A1.v, bh2, acc2_1, 0, 0, 0);
        acc2_1 = __builtin_amdgcn_mfma_f32_16x16x32_bf16(A1.v, bl2, acc2_1, 0, 0, 0);
        acc3_0 = __builtin_amdgcn_mfma_f32_16x16x32_bf16(A0.v, bh3, acc3_0, 0, 0, 0);
        acc3_0 = __builtin_amdgcn_mfma_f32_16x16x32_bf16(A0.v, bl3, acc3_0, 0, 0, 0);
        acc3_1 = __builtin_amdgcn_mfma_f32_16x16x32_bf16(A1.v, bh3, acc3_1, 0, 0, 0);
        acc3_1 = __builtin_amdgcn_mfma_f32_16x16x32_bf16(A1.v, bl3, acc3_1, 0, 0, 0);

        // advance
        pB0 += 32; pB1 += 32; pB2 += 32; pB3 += 32;
        q0 = nq0; q1 = nq1; w0 = nw0; w1 = nw1;
    }

    // ---- epilogue ----
    // wave-local row-sum reduce: lanes {r, r+16, r+32, r+48} hold k-slices of row r
    sp0 += __shfl_xor(sp0, 16, 64); sp0 += __shfl_xor(sp0, 32, 64);
    sp1 += __shfl_xor(sp1, 16, 64); sp1 += __shfl_xor(sp1, 32, 64);
    if (lane < 16) {
        row_ps[w * 32 + lane] = sp0;
        row_ps[w * 32 + 16 + lane] = sp1;
    }
    // write this wave's partial image, col-major [col][row] f32, XOR-swizzled
    // 16B chunks (chunk = col*8 + mi*4 + kg, key = col&7) -> 2-way max on write
    {
        char* img = lds + w * 8192;
#define STACC(NI, MI, A) { int ch = (((NI)*16 + r_c) * 8 + (MI)*4 + kg) ^ (r_c & 7); \
                           *(f32x4*)(img + ch * 16) = (A); }
        STACC(0, 0, acc0_0) STACC(0, 1, acc0_1)
        STACC(1, 0, acc1_0) STACC(1, 1, acc1_1)
        STACC(2, 0, acc2_0) STACC(2, 1, acc2_1)
        STACC(3, 0, acc3_0) STACC(3, 1, acc3_1)
#undef STACC
    }
    __syncthreads();
    if (tid < 32) {
        float t = 0.f;
#pragma unroll
        for (int ww = 0; ww < 8; ++ww) t += row_ps[ww * 32 + tid];
        row_inv[tid] = 1.0f / t;
    }
    __syncthreads();

    // merge 8 images + normalize + store. wave w: cols w*8+(lane>>3), rows (lane&7)*4..+3
    {
        int colg = w * 8 + (lane >> 3);
        int rq = lane & 7;
        int ch = (colg * 8 + rq) ^ (colg & 7);
        f32x4 v = {0, 0, 0, 0};
#pragma unroll
        for (int im = 0; im < 8; ++im)
            v += *(const f32x4*)(lds + im * 8192 + ch * 16);
        f32x4 rinv = *(const f32x4*)((char*)row_inv + rq * 16);
        float* ob = out + ((size_t)b * NN + i0 + rq * 4) * FF + half * 64 + colg;
#pragma unroll
        for (int q = 0; q < 4; ++q)
            ob[(size_t)q * FF] = v[q] * rinv[q];
    }
}

// ---------------------------------------------------------------------------
extern "C" void kernel_launch(void* const* d_in, const int* in_sizes, int n_in,
                              void* d_out, int out_size, void* d_ws, size_t ws_size,
                              hipStream_t stream) {
    const float* h   = (const float*)d_in[0];
    const int*   adj = (const int*)d_in[1];
    const float* W   = (const float*)d_in[2];
    const float* a   = (const float*)d_in[3];
    float* out = (float*)d_out;

    short* WhHiT = (short*)d_ws;                          // 2.13 MB
    short* WhLoT = WhHiT + (size_t)BB * FF * NP;          // 2.13 MB
    float* f1 = (float*)(WhLoT + (size_t)BB * FF * NP);   // 32 KB
    float* f2 = f1 + (size_t)BB * NN;                     // 32 KB
    u32* adjp = (u32*)(f2 + (size_t)BB * NN);             // 512 KB (total ~4.83 MB, proven)

    k_wh<<<(BB * NN) / 16, 256, 0, stream>>>(h, W, a, adj, WhHiT, WhLoT, f1, f2, adjp);
    k_attn<<<512, 512, 0, stream>>>(WhHiT, WhLoT, adjp, f1, f2, out);
}

// Round 12
// 124.270 us; speedup vs baseline: 2.1062x; 1.0405x over previous
//
#include <hip/hip_runtime.h>

#define BB 4
#define NN 2048
#define FF 128
#define NP 2176  // padded WhT row stride (shorts)
#define ALPHA 0.2f
#define SHIFT_C 16.0f  // exp(x-16): x=LR(f1+f2) bounded ~|10|; masked -> p=0 via bit-multiply

typedef short bf16x8 __attribute__((ext_vector_type(8)));
typedef float f32x4 __attribute__((ext_vector_type(4)));
typedef unsigned u32;

__device__ inline short f2bf(float f) {  // RNE float -> bf16 bits
    union { float f; unsigned u; } v; v.f = f;
    unsigned r = (v.u + 0x7FFFu + ((v.u >> 16) & 1u)) >> 16;
    return (short)r;
}
__device__ inline float bf2f(short s) {
    union { float f; unsigned u; } v;
    v.u = ((unsigned)(unsigned short)s) << 16;
    return v.f;
}

// ---------------------------------------------------------------------------
// k_wh v2 (passed R11; neutral vs v1 -- kept for the cleaner store path).
// ---------------------------------------------------------------------------
__global__ __launch_bounds__(256) void k_wh(const float* __restrict__ h,
                                            const float* __restrict__ W,
                                            const float* __restrict__ a,
                                            const int* __restrict__ adj,
                                            short* __restrict__ WhHiT,
                                            short* __restrict__ WhLoT,
                                            float* __restrict__ f1,
                                            float* __restrict__ f2,
                                            u32* __restrict__ adjp) {
    __shared__ float Wa[2 * FF];
    __shared__ float hs[16 * 132];  // 8.25 KB: h-stage (16x128 used) then fp32 transpose tile
    int tid = threadIdx.x;
    int r0 = blockIdx.x * 16;

    {
        int fin = tid & 127;
        const float* av = (tid < 128) ? a : (a + FF);
        const float* wr = W + (size_t)fin * FF;
        float s = 0.f;
        for (int o = 0; o < FF; o += 4) {
            float4 wv = *(const float4*)(wr + o);
            float4 avv = *(const float4*)(av + o);
            s += wv.x * avv.x + wv.y * avv.y + wv.z * avv.z + wv.w * avv.w;
        }
        Wa[(tid < 128 ? 0 : FF) + fin] = s;
    }
    {
        const float4* src = (const float4*)(h + (size_t)r0 * FF);
        float4* dst = (float4*)hs;
        dst[tid] = src[tid];
        dst[256 + tid] = src[256 + tid];
    }
    // de-serialized adj pack: 512 blocks * 256 thr = 131072 = 2048 rows * 64 words
    {
        int g = blockIdx.x * 256 + tid;
        int row = g >> 6, wd = g & 63;
        const int4* ar = (const int4*)(adj + (size_t)row * NN + wd * 32);
        u32 word = 0;
#pragma unroll
        for (int q = 0; q < 8; ++q) {
            int4 v = ar[q];
            word |= (u32)(v.x > 0) << (q * 4);
            word |= (u32)(v.y > 0) << (q * 4 + 1);
            word |= (u32)(v.z > 0) << (q * 4 + 2);
            word |= (u32)(v.w > 0) << (q * 4 + 3);
        }
        adjp[row * 64 + wd] = word;
    }
    __syncthreads();

    {
        int w = tid >> 6, lane = tid & 63;
        float wa1_0 = Wa[lane], wa1_1 = Wa[lane + 64];
        float wa2_0 = Wa[FF + lane], wa2_1 = Wa[FF + lane + 64];
        for (int rr = 0; rr < 4; ++rr) {
            int rloc = w * 4 + rr;
            int row = r0 + rloc;
            float x0 = hs[rloc * FF + lane], x1 = hs[rloc * FF + lane + 64];
            float s1 = x0 * wa1_0 + x1 * wa1_1;
            float s2 = x0 * wa2_0 + x1 * wa2_1;
#pragma unroll
            for (int m = 32; m >= 1; m >>= 1) {
                s1 += __shfl_xor(s1, m, 64);
                s2 += __shfl_xor(s2, m, 64);
            }
            if (lane == 0) { f1[row] = s1; f2[row] = s2; }
        }
    }

    int f4 = (tid & 31) * 4;
    int rg = tid >> 5;  // 0..7
    float acc[2][4];
#pragma unroll
    for (int rr = 0; rr < 2; ++rr)
#pragma unroll
        for (int cc = 0; cc < 4; ++cc) acc[rr][cc] = 0.f;

    for (int k0 = 0; k0 < FF; k0 += 4) {
        float4 wv[4];
#pragma unroll
        for (int kk = 0; kk < 4; ++kk)
            wv[kk] = *(const float4*)(W + (size_t)(k0 + kk) * FF + f4);
        float4 hv[2];
#pragma unroll
        for (int rr = 0; rr < 2; ++rr)
            hv[rr] = *(const float4*)(hs + (rg * 2 + rr) * FF + k0);
#pragma unroll
        for (int rr = 0; rr < 2; ++rr) {
            float hk[4] = {hv[rr].x, hv[rr].y, hv[rr].z, hv[rr].w};
#pragma unroll
            for (int kk = 0; kk < 4; ++kk) {
                acc[rr][0] += hk[kk] * wv[kk].x;
                acc[rr][1] += hk[kk] * wv[kk].y;
                acc[rr][2] += hk[kk] * wv[kk].z;
                acc[rr][3] += hk[kk] * wv[kk].w;
            }
        }
    }

    // LDS transpose + coalesced 16B stores
    __syncthreads();
    {
#pragma unroll
        for (int rr = 0; rr < 2; ++rr)
            *(float4*)(hs + (rg * 2 + rr) * 132 + f4) =
                make_float4(acc[rr][0], acc[rr][1], acc[rr][2], acc[rr][3]);
    }
    __syncthreads();
    {
        int fo = tid >> 1, jh = tid & 1;
        bf16x8 hv_, lv_;
#pragma unroll
        for (int jj = 0; jj < 8; ++jj) {
            float v = hs[(jh * 8 + jj) * 132 + fo];
            short hh = f2bf(v);
            hv_[jj] = hh;
            lv_[jj] = f2bf(v - bf2f(hh));
        }
        int b = r0 >> 11;
        int j0 = (r0 & (NN - 1)) + jh * 8;
        size_t off = (size_t)(b * FF + fo) * NP + j0;
        *(bf16x8*)(WhHiT + off) = hv_;
        *(bf16x8*)(WhLoT + off) = lv_;
    }
}

// ---------------------------------------------------------------------------
// k_attn v15 "64-row x 32-fo re-tile": v8's wave-autonomous full-unroll
// structure (best measured) with 2x MFMA per B-load. Block = 64 rows x
// 32 fo (512 blocks = 4b x 32 tiles x 4 fo-quarters; same grid, same 2
// blocks/CU). Per wave per step: 4 B-loads (was 8) + 32 EV (was 16) +
// 16 MFMA (same). Total B L2 traffic halves 268->134 MB; per-step
// independent VALU work doubles -> covers L2 latency. EV duplication x4
// (~7.7us aggregate, cheap). acc{ni}_{mi}: ni 0..1 x mi 0..3.
// Epilogue = v8 merge generalized to 64-row images (8 x 8KB, row_ps[8][64]).
// ---------------------------------------------------------------------------
#define EV(f2v, f1v, wv, bi) ({ float _t = (f1v) + (f2v); float _x = fmaxf(_t, ALPHA * _t); \
    __expf(_x - SHIFT_C) * (float)(((wv) >> (bi)) & 1u); })

// one A-fragment build: 8 EV -> 4 cvt_pk words, accumulating into SP
#define BUILD_A(Adst, F1V, WV, SP) { \
    float pa, pb; \
    pa = EV(q0.x, F1V, WV, bb + 0); pb = EV(q0.y, F1V, WV, bb + 1); \
    SP += pa + pb; \
    asm("v_cvt_pk_bf16_f32 %0, %1, %2" : "=v"(Adst.u[0]) : "v"(pa), "v"(pb)); \
    pa = EV(q0.z, F1V, WV, bb + 2); pb = EV(q0.w, F1V, WV, bb + 3); \
    SP += pa + pb; \
    asm("v_cvt_pk_bf16_f32 %0, %1, %2" : "=v"(Adst.u[1]) : "v"(pa), "v"(pb)); \
    pa = EV(q1.x, F1V, WV, bb + 4); pb = EV(q1.y, F1V, WV, bb + 5); \
    SP += pa + pb; \
    asm("v_cvt_pk_bf16_f32 %0, %1, %2" : "=v"(Adst.u[2]) : "v"(pa), "v"(pb)); \
    pa = EV(q1.z, F1V, WV, bb + 6); pb = EV(q1.w, F1V, WV, bb + 7); \
    SP += pa + pb; \
    asm("v_cvt_pk_bf16_f32 %0, %1, %2" : "=v"(Adst.u[3]) : "v"(pa), "v"(pb)); }

__global__ __launch_bounds__(512, 4) void k_attn(const short* __restrict__ WhHiT,
                                                 const short* __restrict__ WhLoT,
                                                 const u32* __restrict__ adjp,
                                                 const float* __restrict__ f1,
                                                 const float* __restrict__ f2,
                                                 float* __restrict__ out) {
    __shared__ __align__(16) char lds[67840];  // 8 x 8KB images + row_ps[8][64] + row_inv[64]
    float* row_ps = (float*)(lds + 65536);     // [8][64]
    float* row_inv = (float*)(lds + 67584);    // [64]

    int tid = threadIdx.x;
    int w = tid >> 6, lane = tid & 63;
    int blk = blockIdx.x;                      // 512 = 4 b x 32 tile(64 rows) x 4 qt
    int b = blk >> 7;
    int tile = (blk >> 2) & 31;
    int qt = blk & 3;
    int i0 = tile * 64;

    int r_c = lane & 15, kg = lane >> 4;

    const float* f2b = f2 + b * NN;
    float f10 = f1[b * NN + i0 + r_c];
    float f11 = f1[b * NN + i0 + 16 + r_c];
    float f12 = f1[b * NN + i0 + 32 + r_c];
    float f13 = f1[b * NN + i0 + 48 + r_c];
    const u32* ap0 = adjp + (size_t)(i0 + r_c) * 64;
    const u32* ap1 = adjp + (size_t)(i0 + 16 + r_c) * 64;
    const u32* ap2 = adjp + (size_t)(i0 + 32 + r_c) * 64;
    const u32* ap3 = adjp + (size_t)(i0 + 48 + r_c) * 64;

    // B-fragment row pointers (hi); lo at constant element delta
    const ptrdiff_t dLo = (ptrdiff_t)BB * FF * NP;
    int s0 = w * 8;  // this wave's 8 contiguous j-steps
    const short* pB0 = WhHiT + (size_t)(b * FF + qt * 32 + 0 * 16 + r_c) * NP + s0 * 32 + kg * 8;
    const short* pB1 = WhHiT + (size_t)(b * FF + qt * 32 + 1 * 16 + r_c) * NP + s0 * 32 + kg * 8;

    f32x4 acc0_0 = {0,0,0,0}, acc0_1 = {0,0,0,0}, acc0_2 = {0,0,0,0}, acc0_3 = {0,0,0,0};
    f32x4 acc1_0 = {0,0,0,0}, acc1_1 = {0,0,0,0}, acc1_2 = {0,0,0,0}, acc1_3 = {0,0,0,0};
    float sp0 = 0.f, sp1 = 0.f, sp2 = 0.f, sp3 = 0.f;

    // prologue: scalars for step s0
    float4 q0 = *(const float4*)(f2b + s0 * 32 + kg * 8);
    float4 q1 = *(const float4*)(f2b + s0 * 32 + kg * 8 + 4);
    u32 w0 = ap0[s0], w1 = ap1[s0], w2 = ap2[s0], w3 = ap3[s0];

#pragma unroll
    for (int s8 = 0; s8 < 8; ++s8) {
        // B loads for this step (4 x 16B; consumed after ~700cy of e-compute)
        bf16x8 bh0 = *(const bf16x8*)(pB0); bf16x8 bl0 = *(const bf16x8*)(pB0 + dLo);
        bf16x8 bh1 = *(const bf16x8*)(pB1); bf16x8 bl1 = *(const bf16x8*)(pB1 + dLo);
        // prefetch next step's scalars (wrap harmless)
        int sn = (s0 + s8 + 1) & 63;
        float4 nq0 = *(const float4*)(f2b + sn * 32 + kg * 8);
        float4 nq1 = *(const float4*)(f2b + sn * 32 + kg * 8 + 4);
        u32 nw0 = ap0[sn], nw1 = ap1[sn], nw2 = ap2[sn], nw3 = ap3[sn];

        // in-register A fragments: lane holds rows mi*16 + r_c, k = s*32 + kg*8 + e
        union { u32 u[4]; bf16x8 v; } A0, A1, A2, A3;
        int bb = kg * 8;
        BUILD_A(A0, f10, w0, sp0)
        BUILD_A(A1, f11, w1, sp1)
        BUILD_A(A2, f12, w2, sp2)
        BUILD_A(A3, f13, w3, sp3)

        // 16 MFMA: acc{ni}_{mi} += A{mi} x (Bhi+Blo){ni}
        acc0_0 = __builtin_amdgcn_mfma_f32_16x16x32_bf16(A0.v, bh0, acc0_0, 0, 0, 0);
        acc0_0 = __builtin_amdgcn_mfma_f32_16x16x32_bf16(A0.v, bl0, acc0_0, 0, 0, 0);
        acc0_1 = __builtin_amdgcn_mfma_f32_16x16x32_bf16(A1.v, bh0, acc0_1, 0, 0, 0);
        acc0_1 = __builtin_amdgcn_mfma_f32_16x16x32_bf16(A1.v, bl0, acc0_1, 0, 0, 0);
        acc0_2 = __builtin_amdgcn_mfma_f32_16x16x32_bf16(A2.v, bh0, acc0_2, 0, 0, 0);
        acc0_2 = __builtin_amdgcn_mfma_f32_16x16x32_bf16(A2.v, bl0, acc0_2, 0, 0, 0);
        acc0_3 = __builtin_amdgcn_mfma_f32_16x16x32_bf16(A3.v, bh0, acc0_3, 0, 0, 0);
        acc0_3 = __builtin_amdgcn_mfma_f32_16x16x32_bf16(A3.v, bl0, acc0_3, 0, 0, 0);
        acc1_0 = __builtin_amdgcn_mfma_f32_16x16x32_bf16(A0.v, bh1, acc1_0, 0, 0, 0);
        acc1_0 = __builtin_amdgcn_mfma_f32_16x16x32_bf16(A0.v, bl1, acc1_0, 0, 0, 0);
        acc1_1 = __builtin_amdgcn_mfma_f32_16x16x32_bf16(A1.v, bh1, acc1_1, 0, 0, 0);
        acc1_1 = __builtin_amdgcn_mfma_f32_16x16x32_bf16(A1.v, bl1, acc1_1, 0, 0, 0);
        acc1_2 = __builtin_amdgcn_mfma_f32_16x16x32_bf16(A2.v, bh1, acc1_2, 0, 0, 0);
        acc1_2 = __builtin_amdgcn_mfma_f32_16x16x32_bf16(A2.v, bl1, acc1_2, 0, 0, 0);
        acc1_3 = __builtin_amdgcn_mfma_f32_16x16x32_bf16(A3.v, bh1, acc1_3, 0, 0, 0);
        acc1_3 = __builtin_amdgcn_mfma_f32_16x16x32_bf16(A3.v, bl1, acc1_3, 0, 0, 0);

        // advance
        pB0 += 32; pB1 += 32;
        q0 = nq0; q1 = nq1; w0 = nw0; w1 = nw1; w2 = nw2; w3 = nw3;
    }

    // ---- epilogue ----
    // row sums: lanes {r_c, +16, +32, +48} hold k-slices of the same rows
    sp0 += __shfl_xor(sp0, 16, 64); sp0 += __shfl_xor(sp0, 32, 64);
    sp1 += __shfl_xor(sp1, 16, 64); sp1 += __shfl_xor(sp1, 32, 64);
    sp2 += __shfl_xor(sp2, 16, 64); sp2 += __shfl_xor(sp2, 32, 64);
    sp3 += __shfl_xor(sp3, 16, 64); sp3 += __shfl_xor(sp3, 32, 64);
    if (lane < 16) {
        row_ps[w * 64 + lane]      = sp0;
        row_ps[w * 64 + 16 + lane] = sp1;
        row_ps[w * 64 + 32 + lane] = sp2;
        row_ps[w * 64 + 48 + lane] = sp3;
    }
    // write this wave's partial image: [32 cols][16 row-quads] f32x4, XOR-swizzled
    {
        char* img = lds + w * 8192;
#define STACC(NI, MI, A) { int ch = (((NI)*16 + r_c) * 16 + (MI)*4 + kg) ^ (r_c & 7); \
                           *(f32x4*)(img + ch * 16) = (A); }
        STACC(0, 0, acc0_0) STACC(0, 1, acc0_1) STACC(0, 2, acc0_2) STACC(0, 3, acc0_3)
        STACC(1, 0, acc1_0) STACC(1, 1, acc1_1) STACC(1, 2, acc1_2) STACC(1, 3, acc1_3)
#undef STACC
    }
    __syncthreads();
    if (tid < 64) {
        float t = 0.f;
#pragma unroll
        for (int ww = 0; ww < 8; ++ww) t += row_ps[ww * 64 + tid];
        row_inv[tid] = 1.0f / t;
    }
    __syncthreads();

    // merge 8 images + normalize + store.
    // wave w: cols w*4 + (lane>>4) (0..31 within quarter), row-quads rq = lane&15
    {
        int colg = w * 4 + (lane >> 4);
        int rq = lane & 15;
        int ch = (colg * 16 + rq) ^ (colg & 7);
        f32x4 v = {0, 0, 0, 0};
#pragma unroll
        for (int im = 0; im < 8; ++im)
            v += *(const f32x4*)(lds + im * 8192 + ch * 16);
        f32x4 rinv = *(const f32x4*)((char*)row_inv + rq * 16);
        float* ob = out + ((size_t)b * NN + i0 + rq * 4) * FF + qt * 32 + colg;
#pragma unroll
        for (int q = 0; q < 4; ++q)
            ob[(size_t)q * FF] = v[q] * rinv[q];
    }
}

// ---------------------------------------------------------------------------
extern "C" void kernel_launch(void* const* d_in, const int* in_sizes, int n_in,
                              void* d_out, int out_size, void* d_ws, size_t ws_size,
                              hipStream_t stream) {
    const float* h   = (const float*)d_in[0];
    const int*   adj = (const int*)d_in[1];
    const float* W   = (const float*)d_in[2];
    const float* a   = (const float*)d_in[3];
    float* out = (float*)d_out;

    short* WhHiT = (short*)d_ws;                          // 2.13 MB
    short* WhLoT = WhHiT + (size_t)BB * FF * NP;          // 2.13 MB
    float* f1 = (float*)(WhLoT + (size_t)BB * FF * NP);   // 32 KB
    float* f2 = f1 + (size_t)BB * NN;                     // 32 KB
    u32* adjp = (u32*)(f2 + (size_t)BB * NN);             // 512 KB (total ~4.83 MB, proven)

    k_wh<<<(BB * NN) / 16, 256, 0, stream>>>(h, W, a, adj, WhHiT, WhLoT, f1, f2, adjp);
    k_attn<<<512, 512, 0, stream>>>(WhHiT, WhLoT, adjp, f1, f2, out);
}